// Round 6
// baseline (289.689 us; speedup 1.0000x reference)
//
#include <hip/hip_runtime.h>
#include <cmath>

// Problem geometry (fixed: im is (1, 4096, 4096, 3) f32 NHWC)
constexpr int H    = 4096;
constexpr int W    = 4096;
constexpr int C    = 3;
constexpr int WF   = W * C;      // 12288 floats per image row
constexpr int TW   = 2048;       // tile width in floats per block
constexpr int HALF = TW / 2;     // 1024
constexpr int RPT  = 8;          // output rows per block

typedef float f32x4 __attribute__((ext_vector_type(4)));  // nt-store friendly

__device__ __forceinline__ float ans1(float v) {
    return 2.0f * __builtin_amdgcn_sqrtf(v + 0.375f);
}
__device__ __forceinline__ float4 ans4(float4 v) {
    return make_float4(ans1(v.x), ans1(v.y), ans1(v.z), ans1(v.w));
}

// Fused Anscombe -> separable 3x3 Gaussian (zero pad) -> clip -> inverse
// Anscombe. Thread-independent, split-tile ownership: thread owns float4 at
// p = base+4*tid (lower half) and q = p+1024 (upper half), so EVERY wave-wide
// load and store instruction covers a contiguous 1KB span (no partial-sector
// write amplification; R5's interleaved EPT=8 pattern cost +12% WRITE_SIZE).
// Horizontal +-3 taps come from the two adjacent aligned float4s (neighbor
// threads' core data -> L1 hits). Vertical 3-tap = rolling register window;
// next row prefetched depth-1. No LDS, no barriers, no cross-lane ops.
__global__ __launch_bounds__(256, 8) void anscombe_gauss_kernel(
    const float* __restrict__ in, float* __restrict__ out,
    float wa, float wb, float c1, float c3)
{
    const int tid = threadIdx.x;
    const int p   = blockIdx.x * TW + tid * 4;   // lower-half float4
    const int q   = p + HALF;                    // upper-half float4
    const int h0  = blockIdx.y * RPT;

    // Only two lanes in the whole grid touch a row edge:
    const bool okL0 = (p >= 4);         // left halo of lower half (bx==0,tid==0)
    const bool okR1 = (q + 8 <= WF);    // right halo of upper half (last tile, tid==255)
    const int offL0 = okL0 ? p - 4 : p;
    const int offR1 = okR1 ? q + 4 : q;

    const float4 cfill = make_float4(-0.375f, -0.375f, -0.375f, -0.375f);

    auto loadrow = [&](int h, float4& c0, float4& l0, float4& r0,
                               float4& c1v, float4& l1, float4& r1) {
        if ((unsigned)h < (unsigned)H) {
            const float* rp = in + (long)h * WF;
            l0  = *(const float4*)(rp + offL0);
            c0  = *(const float4*)(rp + p);
            r0  = *(const float4*)(rp + p + 4);      // always in-row (p+8 <= WF)
            l1  = *(const float4*)(rp + q - 4);      // always in-row (q >= 1024)
            c1v = *(const float4*)(rp + q);
            r1  = *(const float4*)(rp + offR1);
            if (!okL0) l0 = cfill;                   // 1 lane in grid
            if (!okR1) r1 = cfill;                   // 1 lane in grid
        } else {
            c0 = l0 = r0 = c1v = l1 = r1 = cfill;    // zero row in AT domain
        }
    };

    float4 pc0, pl0, pr0, pc1, pl1, pr1;
    loadrow(h0 - 1, pc0, pl0, pr0, pc1, pl1, pr1);

    float hp[8] = {0,0,0,0,0,0,0,0};
    float hc[8] = {0,0,0,0,0,0,0,0};

    #pragma unroll
    for (int s = 0; s < RPT + 2; ++s) {
        const float4 vc0 = pc0, vl0 = pl0, vr0 = pr0;
        const float4 vc1 = pc1, vl1 = pl1, vr1 = pr1;
        if (s < RPT + 1) loadrow(h0 + s, pc0, pl0, pr0, pc1, pl1, pr1);

        const float4 a0 = ans4(vc0), aL0 = ans4(vl0), aR0 = ans4(vr0);
        const float4 a1 = ans4(vc1), aL1 = ans4(vl1), aR1 = ans4(vr1);

        float hn[8];
        hn[0] = wa * (aL0.y + a0.w)  + wb * a0.x;
        hn[1] = wa * (aL0.z + aR0.x) + wb * a0.y;
        hn[2] = wa * (aL0.w + aR0.y) + wb * a0.z;
        hn[3] = wa * (a0.x  + aR0.z) + wb * a0.w;
        hn[4] = wa * (aL1.y + a1.w)  + wb * a1.x;
        hn[5] = wa * (aL1.z + aR1.x) + wb * a1.y;
        hn[6] = wa * (aL1.w + aR1.y) + wb * a1.z;
        hn[7] = wa * (a1.x  + aR1.z) + wb * a1.w;

        if (s >= 2) {
            const int ho = h0 + s - 2;
            float o[8];
            #pragma unroll
            for (int j = 0; j < 8; ++j) {
                float y = wa * (hp[j] + hn[j]) + wb * hc[j];
                y = fminf(fmaxf(y, 0.0f), 255.0f);
                // y >= ~0.17 always (center tap always in-image): rcp safe
                float ry = __builtin_amdgcn_rcpf(y);
                o[j] = fmaf(0.25f * y, y,
                        fmaf(ry, fmaf(ry, fmaf(ry, c3, -1.375f), c1), -0.125f));
            }
            float* op = out + (long)ho * WF;
            f32x4 o0 = {o[0], o[1], o[2], o[3]};
            f32x4 o1 = {o[4], o[5], o[6], o[7]};
            __builtin_nontemporal_store(o0, (f32x4*)(op + p));
            __builtin_nontemporal_store(o1, (f32x4*)(op + q));
        }
        #pragma unroll
        for (int j = 0; j < 8; ++j) { hp[j] = hc[j]; hc[j] = hn[j]; }
    }
}

extern "C" void kernel_launch(void* const* d_in, const int* in_sizes, int n_in,
                              void* d_out, int out_size, void* d_ws, size_t ws_size,
                              hipStream_t stream) {
    const float* in = (const float*)d_in[0];
    float* out      = (float*)d_out;

    // Separable Gaussian weights (double precision on host).
    // 2D normalized kernel == outer([a,b,a],[a,b,a]) with a+b+a == 1.
    const double sig2x2 = 2.0 * 1.3 * 1.3;
    const double e1     = std::exp(-1.0 / sig2x2);
    const double inv1d  = 1.0 / (1.0 + 2.0 * e1);
    const float  wa     = (float)(e1 * inv1d);
    const float  wb     = (float)inv1d;

    const double s  = std::sqrt(1.5);
    const float  c1 = (float)(0.25  * s);
    const float  c3 = (float)(0.625 * s);

    dim3 grid(WF / TW, H / RPT);   // 6 x 512
    anscombe_gauss_kernel<<<grid, 256, 0, stream>>>(in, out, wa, wb, c1, c3);
}

// Round 7
// 87.220 us; speedup vs baseline: 3.3214x; 3.3214x over previous
//
#include <hip/hip_runtime.h>
#include <cmath>

// Problem geometry (fixed: im is (1, 4096, 4096, 3) f32 NHWC)
constexpr int H   = 4096;
constexpr int W   = 4096;
constexpr int C   = 3;
constexpr int WF  = W * C;     // 12288 floats per image row
constexpr int TW  = 1024;      // floats per block = 256 threads * 4
constexpr int RPT = 16;        // output rows per block

__device__ __forceinline__ float ans1(float v) {
    return 2.0f * __builtin_amdgcn_sqrtf(v + 0.375f);
}
__device__ __forceinline__ float4 ans4(float4 v) {
    return make_float4(ans1(v.x), ans1(v.y), ans1(v.z), ans1(v.w));
}

// Fused Anscombe -> separable 3x3 Gaussian (zero pad) -> clip -> inverse
// Anscombe. One float4 per thread per row: every wave-wide load AND store
// instruction spans a contiguous 1KB block (exact-size HBM writes, like R2).
// Horizontal +-3 taps come from directly loading the two adjacent float4s
// (they are neighboring lanes' center loads -> L1 hits, no HBM cost; ~1.5x
// redundant sqrt, VALU has headroom). No LDS, no barriers, no cross-lane ops.
// Vertical 3-tap = rolling register window, next row prefetched depth-1.
// NOTE R6 lesson: do NOT force min-waves above what live state allows --
// launch_bounds(256,8) capped VGPR at 32 and spilled to scratch (3x write,
// 4x fetch amplification, 290us). (256,4) leaves <=128 VGPR: no spill.
__global__ __launch_bounds__(256, 4) void anscombe_gauss_kernel(
    const float* __restrict__ in, float* __restrict__ out,
    float wa, float wb, float c1, float c3)
{
    const int tid = threadIdx.x;
    const int gc  = blockIdx.x * TW + tid * 4;   // this thread's float4 column
    const int h0  = blockIdx.y * RPT;

    // Row-edge lanes (2 in the whole grid): clamp address, fill after load.
    const bool okL = (gc >= 4);          // left-neighbor float4 in-row
    const bool okR = (gc + 8 <= WF);     // right-neighbor float4 in-row
    const int offL = okL ? gc - 4 : gc;
    const int offR = okR ? gc + 4 : gc;

    const float4 cfill = make_float4(-0.375f, -0.375f, -0.375f, -0.375f);

    auto loadrow = [&](int h, float4& c, float4& l, float4& r) {
        if ((unsigned)h < (unsigned)H) {
            const float* rp = in + (long)h * WF;
            c = *(const float4*)(rp + gc);
            l = *(const float4*)(rp + offL);
            r = *(const float4*)(rp + offR);
            if (!okL) l = cfill;         // 1 lane in grid (branch-free select)
            if (!okR) r = cfill;         // 1 lane in grid
        } else {
            c = l = r = cfill;           // OOB row: Anscombe(-0.375) == 0
        }
    };

    float4 pc, pl, pr;
    loadrow(h0 - 1, pc, pl, pr);

    float hp[4] = {0, 0, 0, 0};
    float hc[4] = {0, 0, 0, 0};

    #pragma unroll
    for (int s = 0; s < RPT + 2; ++s) {
        const float4 vc = pc, vl = pl, vr = pr;
        if (s < RPT + 1) loadrow(h0 + s, pc, pl, pr);   // prefetch next row

        const float4 a  = ans4(vc);
        const float4 aL = ans4(vl);
        const float4 aR = ans4(vr);

        float hn[4];
        hn[0] = wa * (aL.y + a.w)  + wb * a.x;
        hn[1] = wa * (aL.z + aR.x) + wb * a.y;
        hn[2] = wa * (aL.w + aR.y) + wb * a.z;
        hn[3] = wa * (a.x  + aR.z) + wb * a.w;

        if (s >= 2) {
            const int ho = h0 + s - 2;
            float o[4];
            #pragma unroll
            for (int j = 0; j < 4; ++j) {
                float y = wa * (hp[j] + hn[j]) + wb * hc[j];
                y = fminf(fmaxf(y, 0.0f), 255.0f);
                // y >= ~0.17 always (center tap always in-image): rcp safe
                float ry = __builtin_amdgcn_rcpf(y);
                o[j] = fmaf(0.25f * y, y,
                        fmaf(ry, fmaf(ry, fmaf(ry, c3, -1.375f), c1), -0.125f));
            }
            *(float4*)(out + (long)ho * WF + gc) =
                make_float4(o[0], o[1], o[2], o[3]);
        }
        #pragma unroll
        for (int j = 0; j < 4; ++j) { hp[j] = hc[j]; hc[j] = hn[j]; }
    }
}

extern "C" void kernel_launch(void* const* d_in, const int* in_sizes, int n_in,
                              void* d_out, int out_size, void* d_ws, size_t ws_size,
                              hipStream_t stream) {
    const float* in = (const float*)d_in[0];
    float* out      = (float*)d_out;

    // Separable Gaussian weights (double precision on host).
    // 2D normalized kernel == outer([a,b,a],[a,b,a]) with a+b+a == 1.
    const double sig2x2 = 2.0 * 1.3 * 1.3;
    const double e1     = std::exp(-1.0 / sig2x2);
    const double inv1d  = 1.0 / (1.0 + 2.0 * e1);
    const float  wa     = (float)(e1 * inv1d);
    const float  wb     = (float)inv1d;

    const double s  = std::sqrt(1.5);
    const float  c1 = (float)(0.25  * s);
    const float  c3 = (float)(0.625 * s);

    dim3 grid(WF / TW, H / RPT);   // 12 x 256
    anscombe_gauss_kernel<<<grid, 256, 0, stream>>>(in, out, wa, wb, c1, c3);
}

// Round 8
// 86.330 us; speedup vs baseline: 3.3556x; 1.0103x over previous
//
#include <hip/hip_runtime.h>
#include <cmath>

// Problem geometry (fixed: im is (1, 4096, 4096, 3) f32 NHWC)
constexpr int H   = 4096;
constexpr int W   = 4096;
constexpr int C   = 3;
constexpr int WF  = W * C;     // 12288 floats per image row
constexpr int TW  = 1024;      // floats per block = 256 threads * 4
constexpr int RPT = 16;        // output rows per block

// sqrt(v + 0.375); the Anscombe 2x factor is folded into the horizontal
// weights on the host (saves 12 v_mul per stage).
__device__ __forceinline__ float sq1(float v) {
    return __builtin_amdgcn_sqrtf(v + 0.375f);
}
__device__ __forceinline__ float4 sq4(float4 v) {
    return make_float4(sq1(v.x), sq1(v.y), sq1(v.z), sq1(v.w));
}

// Fused Anscombe -> separable 3x3 Gaussian (zero pad) -> clip -> inverse
// Anscombe. One float4 per thread per row (every wave-wide load AND store
// spans a contiguous 1KB block -> exact-size HBM writes, verified R7).
// Horizontal +-3 taps: direct load of the two adjacent float4s (neighbor
// lanes' center data -> L1 hits). Vertical 3-tap: rolling register window.
// PREFETCH DEPTH 2: row loads are issued two stages before use (~400 cyc of
// compute to hide L2/L3/HBM latency; depth-1 at R7 stalled every stage ->
// VALUBusy 34%, 3.6 TB/s effective). Live state ~55 VGPR, intentionally kept
// <= 64 so HW occupancy stays 8 waves/SIMD (R6 lesson: never force
// min-waves above live-state needs -- that spilled to scratch, 3x traffic).
__global__ __launch_bounds__(256, 4) void anscombe_gauss_kernel(
    const float* __restrict__ in, float* __restrict__ out,
    float wa2, float wb2, float wa, float wb, float c1, float c3)
{
    const int tid = threadIdx.x;
    const int gc  = blockIdx.x * TW + tid * 4;   // this thread's float4 column
    const int h0  = blockIdx.y * RPT;

    // Row-edge lanes (2 in the whole grid): clamp address, fill after load.
    const bool okL = (gc >= 4);
    const bool okR = (gc + 8 <= WF);
    const int offL = okL ? gc - 4 : gc;
    const int offR = okR ? gc + 4 : gc;

    const float4 cfill = make_float4(-0.375f, -0.375f, -0.375f, -0.375f);

    auto loadrow = [&](int h, float4& c, float4& l, float4& r) {
        if ((unsigned)h < (unsigned)H) {
            const float* rp = in + (long)h * WF;
            c = *(const float4*)(rp + gc);
            l = *(const float4*)(rp + offL);
            r = *(const float4*)(rp + offR);
            if (!okL) l = cfill;         // 1 lane in grid (branch-free select)
            if (!okR) r = cfill;         // 1 lane in grid
        } else {
            c = l = r = cfill;           // OOB row: sqrt(0) == 0 == zero pad
        }
    };

    // Two-slot pipeline: A = row used THIS stage, B = row used NEXT stage.
    float4 Ac, Al, Ar, Bc, Bl, Br;
    loadrow(h0 - 1, Ac, Al, Ar);
    loadrow(h0,     Bc, Bl, Br);

    float hp[4] = {0, 0, 0, 0};
    float hc[4] = {0, 0, 0, 0};

    #pragma unroll
    for (int s = 0; s < RPT + 2; ++s) {
        const float4 vc = Ac, vl = Al, vr = Ar;
        Ac = Bc; Al = Bl; Ar = Br;
        if (s < RPT) loadrow(h0 + s + 1, Bc, Bl, Br);  // used at stage s+2

        const float4 a  = sq4(vc);
        const float4 aL = sq4(vl);
        const float4 aR = sq4(vr);

        float hn[4];
        hn[0] = wa2 * (aL.y + a.w)  + wb2 * a.x;
        hn[1] = wa2 * (aL.z + aR.x) + wb2 * a.y;
        hn[2] = wa2 * (aL.w + aR.y) + wb2 * a.z;
        hn[3] = wa2 * (a.x  + aR.z) + wb2 * a.w;

        if (s >= 2) {
            const int ho = h0 + s - 2;
            float o[4];
            #pragma unroll
            for (int j = 0; j < 4; ++j) {
                float y = wa * (hp[j] + hn[j]) + wb * hc[j];
                y = fminf(fmaxf(y, 0.0f), 255.0f);
                // y >= ~0.17 always (center tap always in-image): rcp safe
                float ry = __builtin_amdgcn_rcpf(y);
                o[j] = fmaf(0.25f * y, y,
                        fmaf(ry, fmaf(ry, fmaf(ry, c3, -1.375f), c1), -0.125f));
            }
            *(float4*)(out + (long)ho * WF + gc) =
                make_float4(o[0], o[1], o[2], o[3]);
        }
        #pragma unroll
        for (int j = 0; j < 4; ++j) { hp[j] = hc[j]; hc[j] = hn[j]; }
    }
}

extern "C" void kernel_launch(void* const* d_in, const int* in_sizes, int n_in,
                              void* d_out, int out_size, void* d_ws, size_t ws_size,
                              hipStream_t stream) {
    const float* in = (const float*)d_in[0];
    float* out      = (float*)d_out;

    // Separable Gaussian weights (double precision on host).
    // 2D normalized kernel == outer([a,b,a],[a,b,a]) with a+b+a == 1.
    const double sig2x2 = 2.0 * 1.3 * 1.3;
    const double e1     = std::exp(-1.0 / sig2x2);
    const double inv1d  = 1.0 / (1.0 + 2.0 * e1);
    const float  wa     = (float)(e1 * inv1d);
    const float  wb     = (float)inv1d;
    // Anscombe's 2x folded into the horizontal pass:
    const float  wa2    = (float)(2.0 * e1 * inv1d);
    const float  wb2    = (float)(2.0 * inv1d);

    const double s  = std::sqrt(1.5);
    const float  c1 = (float)(0.25  * s);
    const float  c3 = (float)(0.625 * s);

    dim3 grid(WF / TW, H / RPT);   // 12 x 256
    anscombe_gauss_kernel<<<grid, 256, 0, stream>>>(in, out, wa2, wb2, wa, wb, c1, c3);
}